// Round 1
// baseline (878.491 us; speedup 1.0000x reference)
//
#include <hip/hip_runtime.h>

typedef unsigned short u16;
typedef __attribute__((ext_vector_type(4))) float f32x4;
typedef __attribute__((ext_vector_type(4))) unsigned short u16x4;
typedef __attribute__((ext_vector_type(8))) unsigned short u16x8;
typedef __attribute__((ext_vector_type(8))) __bf16 bf16x8;

#define BM 128
#define BN 128
#define BK 32

__device__ __forceinline__ u16 f2bf(float f) {
  unsigned int u = __float_as_uint(f);
  u = (u + 0x7FFFu + ((u >> 16) & 1u)) >> 16;   // RNE
  return (u16)u;
}
__device__ __forceinline__ float bf2f(u16 v) {
  return __uint_as_float(((unsigned int)v) << 16);
}

typedef const void __attribute__((address_space(1)))* gas1_t;
typedef void __attribute__((address_space(3)))* las3_t;
__device__ __forceinline__ void gload_lds16(const void* g, void* l) {
  __builtin_amdgcn_global_load_lds((gas1_t)g, (las3_t)l, 16, 0, 0);
}

// ---------------- f32 -> bf16 flat converter ----------------
__global__ __launch_bounds__(256) void conv_f32_bf16(const float* __restrict__ in,
                                                     u16* __restrict__ out, int n8) {
  int i = blockIdx.x * 256 + threadIdx.x;
  if (i >= n8) return;
  const f32x4* p = (const f32x4*)in + (size_t)i * 2;
  f32x4 a = p[0], b = p[1];
  u16x8 o;
  o[0]=f2bf(a[0]); o[1]=f2bf(a[1]); o[2]=f2bf(a[2]); o[3]=f2bf(a[3]);
  o[4]=f2bf(b[0]); o[5]=f2bf(b[1]); o[6]=f2bf(b[2]); o[7]=f2bf(b[3]);
  *((u16x8*)out + i) = o;
}

// ---------- E: f32 -> bf16 rows (padded) + 1/rownorm ----------
__global__ __launch_bounds__(256) void conv_rows_norm(const float* __restrict__ in,
                                                      u16* __restrict__ out,
                                                      float* __restrict__ inv_norm,
                                                      int nrows_in, int D) {
  const int row = blockIdx.x;
  const int tid = threadIdx.x;
  float ss = 0.0f;
  if (row < nrows_in) {
    for (int j = tid * 4; j < D; j += 1024) {
      f32x4 v = *((const f32x4*)(in + (size_t)row * D + j));
      u16x4 o; o[0]=f2bf(v[0]); o[1]=f2bf(v[1]); o[2]=f2bf(v[2]); o[3]=f2bf(v[3]);
      *((u16x4*)(out + (size_t)row * D + j)) = o;
      ss += v[0]*v[0] + v[1]*v[1] + v[2]*v[2] + v[3]*v[3];
    }
  } else {
    for (int j = tid * 4; j < D; j += 1024) {
      u16x4 o = (u16x4)0;
      *((u16x4*)(out + (size_t)row * D + j)) = o;
    }
  }
  for (int off = 32; off > 0; off >>= 1) ss += __shfl_down(ss, off, 64);
  __shared__ float red[4];
  if ((tid & 63) == 0) red[tid >> 6] = ss;
  __syncthreads();
  if (tid == 0) {
    float s = red[0] + red[1] + red[2] + red[3];
    inv_norm[row] = (row < nrows_in) ? (1.0f / sqrtf(s)) : 1.0f;
  }
}

// ---------------- 1/rownorm of a bf16 matrix ----------------
__global__ __launch_bounds__(256) void rownorm_bf16(const u16* __restrict__ in,
                                                    float* __restrict__ inv_norm, int D) {
  const int row = blockIdx.x;
  const int tid = threadIdx.x;
  float ss = 0.0f;
  for (int j = tid * 4; j < D; j += 1024) {
    u16x4 v = *((const u16x4*)(in + (size_t)row * D + j));
    float f0 = bf2f(v[0]), f1 = bf2f(v[1]), f2 = bf2f(v[2]), f3 = bf2f(v[3]);
    ss += f0*f0 + f1*f1 + f2*f2 + f3*f3;
  }
  for (int off = 32; off > 0; off >>= 1) ss += __shfl_down(ss, off, 64);
  __shared__ float red[4];
  if ((tid & 63) == 0) red[tid >> 6] = ss;
  __syncthreads();
  if (tid == 0) inv_norm[row] = 1.0f / sqrtf(red[0] + red[1] + red[2] + red[3]);
}

// ---------------- NT bf16 MFMA GEMM, 128x128 tile ----------------
// C[m][n] = sum_k A[m][k] * B[n][k]   (both row-major, stride K)
// SCALED: store f32  C = acc * rinv[m] * cinv[n], predicate n < Nt
// !SCALED: store bf16 (exact-fit grid)
template<bool SCALED>
__global__ __launch_bounds__(256)
void gemm_nt(const u16* __restrict__ A, const u16* __restrict__ Bm,
             float* __restrict__ Cf, u16* __restrict__ Cbf,
             const float* __restrict__ rinv, const float* __restrict__ cinv,
             int K, int Nt, int ldc)
{
  __shared__ u16 As[BM * BK];
  __shared__ u16 Bs[BN * BK];

  const int tid  = threadIdx.x;
  const int wave = tid >> 6;
  const int lane = tid & 63;
  const int wm = wave >> 1, wn = wave & 1;      // 2x2 waves, 64x64 each
  const int fl = lane & 15, fh = lane >> 4;     // fragment row/col, k-octet
  const int tile_m = blockIdx.x * BM;
  const int tile_n = blockIdx.y * BN;

  // staging: wave covers 32 rows of A-tile and B-tile; lane l -> lds base + l*16B
  const int srow = lane >> 2;           // 0..15
  const int scol = (lane & 3) * 8;      // 0,8,16,24

  const u16* Ag = A  + (size_t)(tile_m + wave * 32 + srow) * K + scol;
  const u16* Bg = Bm + (size_t)(tile_n + wave * 32 + srow) * K + scol;
  u16* AsB = &As[(wave * 32) * BK];
  u16* BsB = &Bs[(wave * 32) * BK];

  f32x4 acc[4][4] = {};

  for (int k0 = 0; k0 < K; k0 += BK) {
    __syncthreads();                      // protect LDS before overwrite
    gload_lds16(Ag,           AsB);
    gload_lds16(Ag + 16 * K,  AsB + 16 * BK);
    gload_lds16(Bg,           BsB);
    gload_lds16(Bg + 16 * K,  BsB + 16 * BK);
    Ag += BK; Bg += BK;
    __syncthreads();                      // drains vmcnt(0): tiles ready

    bf16x8 av[4], bv[4];
#pragma unroll
    for (int mt = 0; mt < 4; ++mt)
      av[mt] = *((const bf16x8*)&As[(wm * 64 + mt * 16 + fl) * BK + fh * 8]);
#pragma unroll
    for (int nt = 0; nt < 4; ++nt)
      bv[nt] = *((const bf16x8*)&Bs[(wn * 64 + nt * 16 + fl) * BK + fh * 8]);
#pragma unroll
    for (int mt = 0; mt < 4; ++mt)
#pragma unroll
      for (int nt = 0; nt < 4; ++nt)
        acc[mt][nt] = __builtin_amdgcn_mfma_f32_16x16x32_bf16(av[mt], bv[nt], acc[mt][nt], 0, 0, 0);
  }

  // epilogue: D layout col = lane&15, row = (lane>>4)*4 + reg  [m89-verified]
  if constexpr (SCALED) {
#pragma unroll
    for (int mt = 0; mt < 4; ++mt) {
      const int r0 = tile_m + wm * 64 + mt * 16 + fh * 4;
      const float t0 = rinv[r0], t1 = rinv[r0 + 1], t2 = rinv[r0 + 2], t3 = rinv[r0 + 3];
#pragma unroll
      for (int nt = 0; nt < 4; ++nt) {
        const int c = tile_n + wn * 64 + nt * 16 + fl;
        if (c < Nt) {
          const float ei = cinv[c];
          f32x4 v = acc[mt][nt];
          float* p = Cf + (size_t)r0 * ldc + c;
          p[0]                 = v[0] * t0 * ei;
          p[(size_t)ldc]       = v[1] * t1 * ei;
          p[(size_t)ldc * 2]   = v[2] * t2 * ei;
          p[(size_t)ldc * 3]   = v[3] * t3 * ei;
        }
      }
    }
  } else {
#pragma unroll
    for (int mt = 0; mt < 4; ++mt) {
      const int r0 = tile_m + wm * 64 + mt * 16 + fh * 4;
#pragma unroll
      for (int nt = 0; nt < 4; ++nt) {
        const int c = tile_n + wn * 64 + nt * 16 + fl;
        u16* p = Cbf + (size_t)r0 * ldc + c;
        f32x4 v = acc[mt][nt];
        p[0]               = f2bf(v[0]);
        p[(size_t)ldc]     = f2bf(v[1]);
        p[(size_t)ldc * 2] = f2bf(v[2]);
        p[(size_t)ldc * 3] = f2bf(v[3]);
      }
    }
  }
}

extern "C" void kernel_launch(void* const* d_in, const int* in_sizes, int n_in,
                              void* d_out, int out_size, void* d_ws, size_t ws_size,
                              hipStream_t stream) {
  const float* x = (const float*)d_in[0];   // (B, D)
  const float* W = (const float*)d_in[1];   // (D, D) [out,in]
  const float* E = (const float*)d_in[2];   // (N, D)
  float* out = (float*)d_out;               // (B, N) f32

  const int Dm = 1024;
  const int B  = in_sizes[0] / Dm;                  // 2048
  const int N  = in_sizes[2] / Dm;                  // 50000
  const int Npad = ((N + BN - 1) / BN) * BN;        // 50048

  char* ws = (char*)d_ws;
  u16* e_bf = (u16*)ws;
  size_t off = (size_t)Npad * Dm * sizeof(u16);
  u16* x_bf = (u16*)(ws + off); off += (size_t)B  * Dm * sizeof(u16);
  u16* w_bf = (u16*)(ws + off); off += (size_t)Dm * Dm * sizeof(u16);
  u16* t_bf = (u16*)(ws + off); off += (size_t)B  * Dm * sizeof(u16);
  float* e_inv = (float*)(ws + off); off += (size_t)Npad * sizeof(float);
  float* t_inv = (float*)(ws + off);

  // 1. dtype conversions (+ E padding & inverse norms)
  conv_f32_bf16<<<(B * Dm / 8 + 255) / 256, 256, 0, stream>>>(x, x_bf, B * Dm / 8);
  conv_f32_bf16<<<(Dm * Dm / 8 + 255) / 256, 256, 0, stream>>>(W, w_bf, Dm * Dm / 8);
  conv_rows_norm<<<Npad, 256, 0, stream>>>(E, e_bf, e_inv, N, Dm);

  // 2. t = x @ W^T  (bf16 out), then 1/||t_row||
  gemm_nt<false><<<dim3(B / BM, Dm / BN), 256, 0, stream>>>(
      x_bf, w_bf, nullptr, t_bf, nullptr, nullptr, Dm, Dm, Dm);
  rownorm_bf16<<<B, 256, 0, stream>>>(t_bf, t_inv, Dm);

  // 3. out = (t @ E^T) * t_inv[m] * e_inv[n]
  gemm_nt<true><<<dim3(B / BM, Npad / BN), 256, 0, stream>>>(
      t_bf, e_bf, out, nullptr, t_inv, e_inv, Dm, N, N);
}

// Round 2
// 805.683 us; speedup vs baseline: 1.0904x; 1.0904x over previous
//
#include <hip/hip_runtime.h>

typedef unsigned short u16;
typedef __attribute__((ext_vector_type(4))) float f32x4;
typedef __attribute__((ext_vector_type(4))) unsigned short u16x4;
typedef __attribute__((ext_vector_type(8))) unsigned short u16x8;
typedef __attribute__((ext_vector_type(8))) __bf16 bf16x8;

#define BM 128
#define BN 128
#define BK 32

__device__ __forceinline__ u16 f2bf(float f) {
  unsigned int u = __float_as_uint(f);
  u = (u + 0x7FFFu + ((u >> 16) & 1u)) >> 16;   // RNE
  return (u16)u;
}
__device__ __forceinline__ float bf2f(u16 v) {
  return __uint_as_float(((unsigned int)v) << 16);
}

typedef const void __attribute__((address_space(1)))* gas1_t;
typedef void __attribute__((address_space(3)))* las3_t;
__device__ __forceinline__ void gload_lds16(const void* g, void* l) {
  __builtin_amdgcn_global_load_lds((gas1_t)g, (las3_t)l, 16, 0, 0);
}

__device__ __forceinline__ void bar() {
  asm volatile("" ::: "memory");
  __builtin_amdgcn_s_barrier();
  asm volatile("" ::: "memory");
}

// ---------------- f32 -> bf16 flat converter ----------------
__global__ __launch_bounds__(256) void conv_f32_bf16(const float* __restrict__ in,
                                                     u16* __restrict__ out, int n8) {
  int i = blockIdx.x * 256 + threadIdx.x;
  if (i >= n8) return;
  const f32x4* p = (const f32x4*)in + (size_t)i * 2;
  f32x4 a = p[0], b = p[1];
  u16x8 o;
  o[0]=f2bf(a[0]); o[1]=f2bf(a[1]); o[2]=f2bf(a[2]); o[3]=f2bf(a[3]);
  o[4]=f2bf(b[0]); o[5]=f2bf(b[1]); o[6]=f2bf(b[2]); o[7]=f2bf(b[3]);
  *((u16x8*)out + i) = o;
}

// ---------- E: f32 -> bf16 rows (padded) + 1/rownorm ----------
__global__ __launch_bounds__(256) void conv_rows_norm(const float* __restrict__ in,
                                                      u16* __restrict__ out,
                                                      float* __restrict__ inv_norm,
                                                      int nrows_in, int D) {
  const int row = blockIdx.x;
  const int tid = threadIdx.x;
  float ss = 0.0f;
  if (row < nrows_in) {
    for (int j = tid * 4; j < D; j += 1024) {
      f32x4 v = *((const f32x4*)(in + (size_t)row * D + j));
      u16x4 o; o[0]=f2bf(v[0]); o[1]=f2bf(v[1]); o[2]=f2bf(v[2]); o[3]=f2bf(v[3]);
      *((u16x4*)(out + (size_t)row * D + j)) = o;
      ss += v[0]*v[0] + v[1]*v[1] + v[2]*v[2] + v[3]*v[3];
    }
  } else {
    for (int j = tid * 4; j < D; j += 1024) {
      u16x4 o = (u16x4)0;
      *((u16x4*)(out + (size_t)row * D + j)) = o;
    }
  }
  for (int off = 32; off > 0; off >>= 1) ss += __shfl_down(ss, off, 64);
  __shared__ float red[4];
  if ((tid & 63) == 0) red[tid >> 6] = ss;
  __syncthreads();
  if (tid == 0) {
    float s = red[0] + red[1] + red[2] + red[3];
    inv_norm[row] = (row < nrows_in) ? (1.0f / sqrtf(s)) : 1.0f;
  }
}

// ---------------- 1/rownorm of a bf16 matrix ----------------
__global__ __launch_bounds__(256) void rownorm_bf16(const u16* __restrict__ in,
                                                    float* __restrict__ inv_norm, int D) {
  const int row = blockIdx.x;
  const int tid = threadIdx.x;
  float ss = 0.0f;
  for (int j = tid * 4; j < D; j += 1024) {
    u16x4 v = *((const u16x4*)(in + (size_t)row * D + j));
    float f0 = bf2f(v[0]), f1 = bf2f(v[1]), f2 = bf2f(v[2]), f3 = bf2f(v[3]);
    ss += f0*f0 + f1*f1 + f2*f2 + f3*f3;
  }
  for (int off = 32; off > 0; off >>= 1) ss += __shfl_down(ss, off, 64);
  __shared__ float red[4];
  if ((tid & 63) == 0) red[tid >> 6] = ss;
  __syncthreads();
  if (tid == 0) inv_norm[row] = 1.0f / sqrtf(red[0] + red[1] + red[2] + red[3]);
}

// ---------------- small NT bf16 MFMA GEMM, 128x128 tile (for t = x W^T) ----
__global__ __launch_bounds__(256)
void gemm_nt_small(const u16* __restrict__ A, const u16* __restrict__ Bm,
                   u16* __restrict__ Cbf, int K, int ldc)
{
  __shared__ u16 As[BM * BK];
  __shared__ u16 Bs[BN * BK];

  const int tid  = threadIdx.x;
  const int wave = tid >> 6;
  const int lane = tid & 63;
  const int wm = wave >> 1, wn = wave & 1;
  const int fl = lane & 15, fh = lane >> 4;
  const int tile_m = blockIdx.x * BM;
  const int tile_n = blockIdx.y * BN;

  const int srow = lane >> 2;
  const int scol = (lane & 3) * 8;

  const u16* Ag = A  + (size_t)(tile_m + wave * 32 + srow) * K + scol;
  const u16* Bg = Bm + (size_t)(tile_n + wave * 32 + srow) * K + scol;
  u16* AsB = &As[(wave * 32) * BK];
  u16* BsB = &Bs[(wave * 32) * BK];

  f32x4 acc[4][4] = {};

  for (int k0 = 0; k0 < K; k0 += BK) {
    __syncthreads();
    gload_lds16(Ag,           AsB);
    gload_lds16(Ag + 16 * K,  AsB + 16 * BK);
    gload_lds16(Bg,           BsB);
    gload_lds16(Bg + 16 * K,  BsB + 16 * BK);
    Ag += BK; Bg += BK;
    __syncthreads();

    bf16x8 av[4], bv[4];
#pragma unroll
    for (int mt = 0; mt < 4; ++mt)
      av[mt] = *((const bf16x8*)&As[(wm * 64 + mt * 16 + fl) * BK + fh * 8]);
#pragma unroll
    for (int nt = 0; nt < 4; ++nt)
      bv[nt] = *((const bf16x8*)&Bs[(wn * 64 + nt * 16 + fl) * BK + fh * 8]);
#pragma unroll
    for (int mt = 0; mt < 4; ++mt)
#pragma unroll
      for (int nt = 0; nt < 4; ++nt)
        acc[mt][nt] = __builtin_amdgcn_mfma_f32_16x16x32_bf16(av[mt], bv[nt], acc[mt][nt], 0, 0, 0);
  }

#pragma unroll
  for (int mt = 0; mt < 4; ++mt) {
    const int r0 = tile_m + wm * 64 + mt * 16 + fh * 4;
#pragma unroll
    for (int nt = 0; nt < 4; ++nt) {
      const int c = tile_n + wn * 64 + nt * 16 + fl;
      u16* p = Cbf + (size_t)r0 * ldc + c;
      f32x4 v = acc[mt][nt];
      p[0]               = f2bf(v[0]);
      p[(size_t)ldc]     = f2bf(v[1]);
      p[(size_t)ldc * 2] = f2bf(v[2]);
      p[(size_t)ldc * 3] = f2bf(v[3]);
    }
  }
}

// ============ main GEMM: 256x256 tile, BK=32, 3-buffer counted-vmcnt pipeline ============
// C[m][n] = (sum_k A[m][k]*B[n][k]) * rinv[m] * cinv[n], f32 out, predicated n < Nvalid.
// LDS layout per 256x32 bf16 tile: 128 "fat rows" of 128 B (two K-rows each),
// 16-B slots XOR-swizzled by (fatrow&7). global_load_lds writes linearly from
// a pre-inverse-swizzled global source (rule 21).
#define GBM 256
#define GBN 256
#define GBK 32
#define TELEM (GBM * GBK)      // 8192 u16 = 16 KB per matrix tile
#define NTM 8                  // M tiles (2048/256), hard-wired

__global__ __launch_bounds__(512, 2)
void gemm_nt_big(const u16* __restrict__ A, const u16* __restrict__ Bm,
                 float* __restrict__ C,
                 const float* __restrict__ rinv, const float* __restrict__ cinv,
                 int K, int NB, int Nvalid, int ldc, int cpx)
{
  __shared__ u16 lds[3 * 2 * TELEM];   // 96 KB: 3 buffers x {A,B}

  const int tt   = threadIdx.x;
  const int wid  = tt >> 6;
  const int lane = tt & 63;
  const int wm = wid >> 2, wn = wid & 3;       // 2 x 4 waves
  const int fl = lane & 15, fh = lane >> 4;
  const int flh = fl >> 1;
  const int swz = ((((fl & 1) << 2) | fh) ^ flh) * 16;   // lane-constant byte offset

  // XCD-aware bijective swizzle: 8 XCDs get contiguous tile-ranges, m fastest.
  const int gid = blockIdx.x;
  const int tl  = (gid & 7) * cpx + (gid >> 3);
  const int tile_m = (tl & (NTM - 1)) * GBM;
  const int tile_n = (tl >> 3) * GBN;

  // ---- staging source (pre-inverse-swizzled) ----
  const int sl   = (tt & 7) ^ ((tt >> 3) & 7);
  const int srow = ((tt >> 3) << 1) + (sl >> 2);   // 0..127
  const int scol = (sl & 3) * 8;

  const u16* Ag0 = A + (size_t)(tile_m + srow) * K + scol;
  const u16* Ag1 = Ag0 + (size_t)128 * K;
  int br0 = tile_n + srow;       if (br0 > NB - 1) br0 = NB - 1;
  int br1 = tile_n + srow + 128; if (br1 > NB - 1) br1 = NB - 1;
  const u16* Bg0 = Bm + (size_t)br0 * K + scol;
  const u16* Bg1 = Bm + (size_t)br1 * K + scol;

#define STAGE_A(sbuf, ko) { char* d_ = (char*)(sbuf) + tt * 16; \
    gload_lds16(Ag0 + (ko), d_); gload_lds16(Ag1 + (ko), d_ + 8192); }
#define STAGE_B(sbuf, ko) { char* d_ = (char*)(sbuf) + tt * 16; \
    gload_lds16(Bg0 + (ko), d_); gload_lds16(Bg1 + (ko), d_ + 8192); }

  u16* A0 = lds;                 u16* B0 = lds + TELEM;
  u16* A1 = lds + 2 * TELEM;     u16* B1 = lds + 3 * TELEM;
  u16* A2 = lds + 4 * TELEM;     u16* B2 = lds + 5 * TELEM;

  f32x4 acc[8][4] = {};

  // prologue: stage tiles 0 and 1; wait tile 0 landed (4 newest stay in flight)
  STAGE_A(A0, 0); STAGE_B(B0, 0);
  STAGE_A(A1, GBK); STAGE_B(B1, GBK);
  asm volatile("s_waitcnt vmcnt(4)" ::: "memory");
  bar();

  u16 *cA = A0, *cB = B0, *nA = A1, *nB = B1, *sA = A2, *sB = B2;
  const int NT = K / GBK;
  int ko = 2 * GBK;                       // k-offset of stage target (tile t+2)
  const int komax = (NT - 1) * GBK;

  for (int t = 0; t < NT; ++t) {
    const char* pA = (const char*)cA;
    const char* pB = (const char*)cB;
    bf16x8 bv[4], av[4];

    // ---- phase 0: read B-frags + A-quad0, stage next+2 A, 16 MFMA ----
#pragma unroll
    for (int j = 0; j < 4; ++j)
      bv[j] = *(const bf16x8*)(pB + ((((wn << 5) + j * 8 + flh) << 7) + swz));
#pragma unroll
    for (int i = 0; i < 4; ++i)
      av[i] = *(const bf16x8*)(pA + ((((wm << 6) + i * 8 + flh) << 7) + swz));
    STAGE_A(sA, ko);
    bar();
    __builtin_amdgcn_s_setprio(1);
#pragma unroll
    for (int i = 0; i < 4; ++i)
#pragma unroll
      for (int j = 0; j < 4; ++j)
        acc[i][j] = __builtin_amdgcn_mfma_f32_16x16x32_bf16(av[i], bv[j], acc[i][j], 0, 0, 0);
    __builtin_amdgcn_s_setprio(0);
    bar();

    // ---- phase 1: read A-quad1, stage next+2 B, 16 MFMA ----
#pragma unroll
    for (int i = 0; i < 4; ++i)
      av[i] = *(const bf16x8*)(pA + ((((wm << 6) + (4 + i) * 8 + flh) << 7) + swz));
    STAGE_B(sB, ko);
    bar();
    __builtin_amdgcn_s_setprio(1);
#pragma unroll
    for (int i = 0; i < 4; ++i)
#pragma unroll
      for (int j = 0; j < 4; ++j)
        acc[4 + i][j] = __builtin_amdgcn_mfma_f32_16x16x32_bf16(av[i], bv[j], acc[4 + i][j], 0, 0, 0);
    __builtin_amdgcn_s_setprio(0);

    // ---- tile boundary: straggler guard + counted vmcnt (never 0) ----
    asm volatile("s_waitcnt lgkmcnt(0)" ::: "memory");
    asm volatile("s_waitcnt vmcnt(4)" ::: "memory");
    bar();

    // rotate buffers: cur <- next <- stage <- cur
    u16 *tA_ = cA, *tB_ = cB;
    cA = nA; cB = nB; nA = sA; nB = sB; sA = tA_; sB = tB_;
    ko += GBK; if (ko > komax) ko = komax;
  }

  // ---- epilogue: scaled f32 stores; D layout col=lane&15, row=(lane>>4)*4+reg ----
#pragma unroll
  for (int mt = 0; mt < 8; ++mt) {
    const int r0 = tile_m + wm * 128 + mt * 16 + fh * 4;
    const float t0 = rinv[r0], t1 = rinv[r0 + 1], t2 = rinv[r0 + 2], t3 = rinv[r0 + 3];
#pragma unroll
    for (int nt = 0; nt < 4; ++nt) {
      const int c = tile_n + wn * 64 + nt * 16 + fl;
      if (c < Nvalid) {
        const float ei = cinv[c];
        f32x4 v = acc[mt][nt];
        float* p = C + (size_t)r0 * ldc + c;
        p[0]               = v[0] * t0 * ei;
        p[(size_t)ldc]     = v[1] * t1 * ei;
        p[(size_t)ldc * 2] = v[2] * t2 * ei;
        p[(size_t)ldc * 3] = v[3] * t3 * ei;
      }
    }
  }
#undef STAGE_A
#undef STAGE_B
}

extern "C" void kernel_launch(void* const* d_in, const int* in_sizes, int n_in,
                              void* d_out, int out_size, void* d_ws, size_t ws_size,
                              hipStream_t stream) {
  const float* x = (const float*)d_in[0];   // (B, D)
  const float* W = (const float*)d_in[1];   // (D, D) [out,in]
  const float* E = (const float*)d_in[2];   // (N, D)
  float* out = (float*)d_out;               // (B, N) f32

  const int Dm = 1024;
  const int B  = in_sizes[0] / Dm;                  // 2048
  const int N  = in_sizes[2] / Dm;                  // 50000
  const int Npad = ((N + BN - 1) / BN) * BN;        // 50048 (e_bf rows)
  const int NTN = (N + GBN - 1) / GBN;              // 196 N-tiles for main GEMM
  const int NWG = NTM * NTN;                        // 1568, divisible by 8

  char* ws = (char*)d_ws;
  u16* e_bf = (u16*)ws;
  size_t off = (size_t)Npad * Dm * sizeof(u16);
  u16* x_bf = (u16*)(ws + off); off += (size_t)B  * Dm * sizeof(u16);
  u16* w_bf = (u16*)(ws + off); off += (size_t)Dm * Dm * sizeof(u16);
  u16* t_bf = (u16*)(ws + off); off += (size_t)B  * Dm * sizeof(u16);
  float* e_inv = (float*)(ws + off); off += (size_t)Npad * sizeof(float);
  float* t_inv = (float*)(ws + off);

  // 1. dtype conversions (+ E padding & inverse norms)
  conv_f32_bf16<<<(B * Dm / 8 + 255) / 256, 256, 0, stream>>>(x, x_bf, B * Dm / 8);
  conv_f32_bf16<<<(Dm * Dm / 8 + 255) / 256, 256, 0, stream>>>(W, w_bf, Dm * Dm / 8);
  conv_rows_norm<<<Npad, 256, 0, stream>>>(E, e_bf, e_inv, N, Dm);

  // 2. t = x @ W^T  (bf16 out), then 1/||t_row||
  gemm_nt_small<<<dim3(B / BM, Dm / BN), 256, 0, stream>>>(x_bf, w_bf, t_bf, Dm, Dm);
  rownorm_bf16<<<B, 256, 0, stream>>>(t_bf, t_inv, Dm);

  // 3. out = (t @ E^T) * t_inv[m] * e_inv[n]  — 256x256 pipelined MFMA kernel
  gemm_nt_big<<<NWG, 512, 0, stream>>>(t_bf, e_bf, out, t_inv, e_inv,
                                       Dm, Npad, N, N, NWG / 8);
}